// Round 7
// baseline (97.062 us; speedup 1.0000x reference)
//
#include <hip/hip_runtime.h>

typedef _Float16 f16;
typedef _Float16 f16x8 __attribute__((ext_vector_type(8)));
typedef _Float16 f16x4 __attribute__((ext_vector_type(4)));
typedef float    f32x4 __attribute__((ext_vector_type(4)));

#define MFMA16(a,b,c) __builtin_amdgcn_mfma_f32_16x16x32_f16((a),(b),(c),0,0,0)
#define AS1(p) ((const __attribute__((address_space(1))) void*)(p))
#define AS3(p) ((__attribute__((address_space(3))) void*)(p))

constexpr int   NH   = 12;
constexpr int   SEQ  = 1024;
constexpr float INV128 = 1.0f/128.0f;
constexpr int   ECAP = 98304;
constexpr float THR_NOT = -4.5948f;   // gap >= this  => certainly NOT flagged
constexpr float THR_YES = -11.5265f;  // gap <  this  => certainly flagged

__device__ __forceinline__ float q8f(float x){ return rintf(x*128.0f)*INV128; }
__device__ __forceinline__ float q4f(float x){ return rintf(x*8.0f)*0.125f; }

// ---------------- K0: quantize fp32 -> fp16 (exact) ----------------
__global__ void quant_f16(const float* __restrict__ in, f16* __restrict__ out, int n){
    int i = (blockIdx.x*256 + threadIdx.x)*4;
    if (i >= n) return;
    float4 v = *(const float4*)(in + i);
    f16x4 o;
    o[0]=(f16)q8f(v.x); o[1]=(f16)q8f(v.y); o[2]=(f16)q8f(v.z); o[3]=(f16)q8f(v.w);
    *(f16x4*)(out + i) = o;
}

// ---------------- K_fill: out = proj_b broadcast; reset counters -------
__global__ void fill_out(float* __restrict__ out, const float* __restrict__ pb,
                         int* __restrict__ cnt, int* __restrict__ cnt2){
    int i = (blockIdx.x*256 + threadIdx.x)*4;
    int c = i % 768;
    float4 v = { pb[c], pb[c+1], pb[c+2], pb[c+3] };
    *(float4*)(out + i) = v;
    if (i == 0){ *cnt = 0; *cnt2 = 0; }
}

// ---------------- K1: QK-only GEMM (8192x1536x768), m97-style ---------------
// writes Qm (q4 of q8) and Km (q4 of q8, pre-scaled by 0.125)
__global__ __launch_bounds__(256) void gemm_qk(
    const f16* __restrict__ Aq, const f16* __restrict__ Wq,
    const float* __restrict__ g, const float* __restrict__ bb,
    f16* __restrict__ Qm, f16* __restrict__ Km)
{
    __shared__ f16 As[128][32];
    __shared__ f16 Bs[128][32];
    const int t = threadIdx.x;
    const int head = blockIdx.x;            // 12 heads = col tiles
    const int row0 = blockIdx.y*128;
    const int wid = t>>6, lane = t&63;
    const int wr = (wid>>1)*64, wc = (wid&1)*64;
    const int lr = lane&15, lg = lane>>4;

    const f16* Asrc = Aq + (size_t)row0*768;
    const f16* Bsrc = Wq + (size_t)(head*384)*768;

    // staging: chunk ci covers rows [ci*16, ci*16+16); lane covers row ci*16+(lane>>2), col (lane&3)*8
    const int r0 = wid*32 + (lane>>2);
    const int scol = (lane&3)*8;
    const f16* a0p = Asrc + (size_t)r0*768 + scol;
    const f16* a1p = a0p + (size_t)16*768;
    const f16* b0p = Bsrc + (size_t)r0*768 + scol;
    const f16* b1p = b0p + (size_t)16*768;
    f16* lA0 = &As[wid*32][0];
    f16* lA1 = &As[wid*32+16][0];
    f16* lB0 = &Bs[wid*32][0];
    f16* lB1 = &Bs[wid*32+16][0];

    f32x4 acc[4][4] = {};
    for (int k0 = 0; k0 < 768; k0 += 32){
        __builtin_amdgcn_global_load_lds(AS1(a0p + k0), AS3(lA0), 16, 0, 0);
        __builtin_amdgcn_global_load_lds(AS1(a1p + k0), AS3(lA1), 16, 0, 0);
        __builtin_amdgcn_global_load_lds(AS1(b0p + k0), AS3(lB0), 16, 0, 0);
        __builtin_amdgcn_global_load_lds(AS1(b1p + k0), AS3(lB1), 16, 0, 0);
        __syncthreads();
        f16x8 af[4], bf[4];
        #pragma unroll
        for (int i=0;i<4;i++){
            af[i] = *(const f16x8*)&As[wr + i*16 + lr][lg*8];
            bf[i] = *(const f16x8*)&Bs[wc + i*16 + lr][lg*8];
        }
        #pragma unroll
        for (int i=0;i<4;i++)
            #pragma unroll
            for (int j=0;j<4;j++)
                acc[i][j] = MFMA16(af[i], bf[j], acc[i][j]);
        __syncthreads();
    }
    #pragma unroll
    for (int j=0;j<4;j++){
        int rr = wc + j*16 + lr;               // 0..127 within head
        int gcol = head*384 + rr;
        float gg = g[gcol], bv = bb[gcol];
        #pragma unroll
        for (int i=0;i<4;i++){
            #pragma unroll
            for (int r=0;r<4;r++){
                int grow = row0 + wr + i*16 + lg*4 + r;
                float h = __fadd_rn(__fmul_rn(acc[i][j][r], gg), bv);
                float v4 = q4f(q8f(h));
                int bq = grow >> 10, n = grow & 1023;
                size_t base = ((size_t)(bq*NH + head)*SEQ + n)*64;
                if (rr < 64) Qm[base + rr]      = (f16)v4;
                else         Km[base + rr - 64] = (f16)(v4 * 0.125f);
            }
        }
    }
}

// ---------------- K2: pass A — exp-free max/second-max/argmax scan ----------
__global__ __launch_bounds__(256) void pass_a(
    const f16* __restrict__ Qm, const f16* __restrict__ Km,
    const float* __restrict__ biases, int NU,
    int* __restrict__ cnt, int2* __restrict__ entries,
    int* __restrict__ cnt2, int2* __restrict__ amb)
{
    __shared__ f16 Qs[64][72];
    __shared__ f16 Ks[64][72];
    __shared__ float bt[1024];

    const int t = threadIdx.x;
    const int qt = blockIdx.x, bh = blockIdx.y;
    const int h = bh % NH;
    const int n0 = qt*64;
    const int lane = t&63, w = t>>6;
    const int lr = lane&15, lg = lane>>4;

    for (int i = t; i < 1024; i += 256) bt[i] = biases[h*NU + i];
    for (int sidx = t; sidx < 512; sidx += 256){
        int r = sidx>>3, q = (sidx&7)*8;
        *(f16x8*)&Qs[r][q] = *(const f16x8*)&Qm[((size_t)bh*SEQ + n0 + r)*64 + q];
    }
    __syncthreads();

    const f16x8 aq0 = *(const f16x8*)&Qs[w*16+lr][lg*8];
    const f16x8 aq1 = *(const f16x8*)&Qs[w*16+lr][32+lg*8];

    const int rn = qt*2 + (w>>1);          // image row of this wave's 16 q-rows
    int cn[4];
    #pragma unroll
    for (int r=0;r<4;r++) cn[r] = (w*16 + lg*4 + r) & 31;

    float mx[4], m2[4]; int ag[4];
    #pragma unroll
    for (int r=0;r<4;r++){ mx[r] = -3e38f; m2[r] = -3e38f; ag[r] = 0; }

    for (int kb = 0; kb < SEQ; kb += 64){
        __syncthreads();
        for (int sidx = t; sidx < 512; sidx += 256){
            int r = sidx>>3, q = (sidx&7)*8;
            *(f16x8*)&Ks[r][q] = *(const f16x8*)&Km[((size_t)bh*SEQ + kb + r)*64 + q];
        }
        __syncthreads();
        #pragma unroll
        for (int ct=0; ct<4; ct++){
            f16x8 b0 = *(const f16x8*)&Ks[ct*16+lr][lg*8];
            f16x8 b1 = *(const f16x8*)&Ks[ct*16+lr][32+lg*8];
            f32x4 c = {};
            c = MFMA16(aq0, b0, c);
            c = MFMA16(aq1, b1, c);
            int m = kb + ct*16 + lr;
            int drb = __builtin_abs(rn - (m>>5))*32;
            int cm = m & 31;
            #pragma unroll
            for (int r=0;r<4;r++){
                int idx = drb + __builtin_abs(cn[r]-cm);
                float sc = c[r] + bt[idx];
                float om = mx[r];
                m2[r] = fmaxf(m2[r], fminf(sc, om));
                ag[r] = (sc > om) ? m : ag[r];
                mx[r] = fmaxf(om, sc);
            }
        }
    }

    #pragma unroll
    for (int r=0;r<4;r++){
        float mxv = mx[r], m2v = m2[r]; int agv = ag[r];
        #pragma unroll
        for (int d=1; d<16; d<<=1){
            float mo  = __shfl_xor(mxv, d);
            float m2o = __shfl_xor(m2v, d);
            int   ago = __shfl_xor(agv, d);
            float sec = fmaxf(fminf(mxv, mo), (mxv >= mo) ? m2v : m2o);
            agv = (mo > mxv) ? ago : agv;
            mxv = fmaxf(mxv, mo);
            m2v = sec;
        }
        if (lr == 0){
            float gap = m2v - mxv;
            if (gap < THR_NOT){
                int n = n0 + w*16 + lg*4 + r;
                int code = (bh<<10) | n;
                if (gap < THR_YES){
                    int pos = atomicAdd(cnt, 1);
                    if (pos < ECAP) entries[pos] = make_int2(code, agv);
                } else {
                    int pos = atomicAdd(cnt2, 1);
                    if (pos < ECAP) amb[pos] = make_int2(code, agv);
                }
            }
        }
    }
}

// ---------------- K2b: exact resolve of ambiguous rows ----------
__global__ __launch_bounds__(256) void resolve_kernel(
    const f16* __restrict__ Qm, const f16* __restrict__ Km,
    const float* __restrict__ biases, int NU,
    const int* __restrict__ cnt2, const int2* __restrict__ amb,
    int* __restrict__ cnt, int2* __restrict__ entries)
{
    __shared__ float qrow[64];
    __shared__ float rmax[4], rsum[4];
    int total = *cnt2; if (total > ECAP) total = ECAP;
    const int t = threadIdx.x;
    for (int e = blockIdx.x; e < total; e += gridDim.x){
        int2 a = amb[e];
        int bh = a.x>>10, n = a.x&1023, h = bh % NH;
        __syncthreads();
        if (t < 64) qrow[t] = (float)Qm[((size_t)bh*SEQ + n)*64 + t];
        __syncthreads();
        int rn = n>>5, cnn = n&31;
        float lmax = -3e38f; float lsc[4];
        #pragma unroll
        for (int j=0;j<4;j++){
            int m = t + j*256;
            const f16* kp = &Km[((size_t)bh*SEQ + m)*64];
            float d = 0.f;
            for (int u=0; u<64; u+=8){
                f16x8 kv = *(const f16x8*)(kp+u);
                #pragma unroll
                for (int z=0; z<8; z++) d += qrow[u+z]*(float)kv[z];
            }
            int idx = __builtin_abs(rn-(m>>5))*32 + __builtin_abs(cnn-(m&31));
            lsc[j] = d + biases[h*NU + idx];
            lmax = fmaxf(lmax, lsc[j]);
        }
        #pragma unroll
        for (int dd=32; dd>=1; dd>>=1) lmax = fmaxf(lmax, __shfl_xor(lmax, dd));
        if ((t&63)==0) rmax[t>>6] = lmax;
        __syncthreads();
        float MX = fmaxf(fmaxf(rmax[0],rmax[1]), fmaxf(rmax[2],rmax[3]));
        float ls = 0.f;
        #pragma unroll
        for (int j=0;j<4;j++) ls += expf(lsc[j]-MX);
        #pragma unroll
        for (int dd=32; dd>=1; dd>>=1) ls += __shfl_xor(ls, dd);
        if ((t&63)==0) rsum[t>>6] = ls;
        __syncthreads();
        if (t==0){
            float SUM = rsum[0]+rsum[1]+rsum[2]+rsum[3];
            if (1.0f/SUM > 0.99f){
                int pos = atomicAdd(cnt, 1);
                if (pos < ECAP) entries[pos] = a;
            }
        }
    }
}

// ---------------- K3: rare-path exact correction (recomputes q,k,v) --------
__global__ __launch_bounds__(256) void correct_kernel(
    const f16* __restrict__ xq, const f16* __restrict__ wq,
    const float* __restrict__ g, const float* __restrict__ bb,
    const float* __restrict__ biases, int NU,
    const float* __restrict__ proj_w, const float* __restrict__ pg,
    const int* __restrict__ cnt, const int2* __restrict__ entries,
    float* __restrict__ out)
{
    __shared__ float xr_n[768], xr_m[768];
    __shared__ float qs[64], ks[64];
    __shared__ float hq[256];
    __shared__ float s_as;
    int total = *cnt; if (total > ECAP) total = ECAP;
    const int t = threadIdx.x;
    for (int e = blockIdx.x; e < total; e += gridDim.x){
        int2 a = entries[e];
        int bh = a.x>>10, n = a.x&1023, ms = a.y;
        int h = bh % NH, b = bh / NH;
        __syncthreads();
        for (int i=t; i<768; i+=256){
            xr_n[i] = (float)xq[((size_t)b*SEQ + n)*768 + i];
            xr_m[i] = (float)xq[((size_t)b*SEQ + ms)*768 + i];
        }
        __syncthreads();
        if (t < 128){
            int col = t & 63;
            int gcol = h*384 + (t<64 ? col : 64+col);
            const f16* wr = &wq[(size_t)gcol*768];
            const float* xr = (t<64) ? xr_n : xr_m;
            float acc = 0.f;
            for (int d=0; d<768; d++) acc = fmaf(xr[d], (float)wr[d], acc);
            float hv = __fadd_rn(__fmul_rn(acc, g[gcol]), bb[gcol]);
            float v = q8f(hv);
            if (t<64) qs[col] = v; else ks[col] = v;
        }
        __syncthreads();
        if (t < 64){
            float p = qs[t]*ks[t];
            #pragma unroll
            for (int d=32; d>=1; d>>=1) p += __shfl_xor(p, d);
            if (t == 0){
                int idx = __builtin_abs((n>>5)-(ms>>5))*32 + __builtin_abs((n&31)-(ms&31));
                float ss = __fadd_rn(__fmul_rn(p, 0.125f), biases[h*NU + idx]);
                float mx2 = fmaxf(ss, 0.f);
                float es = expf(ss-mx2), e0 = expf(-mx2);
                float Z = fmaf(1023.f, e0, es);
                s_as = q8f(es/Z);     // off-argmax weights quantize to exactly 0
            }
        }
        __syncthreads();
        {
            int gcol = h*384 + 128 + t;
            const f16* wr = &wq[(size_t)gcol*768];
            float acc = 0.f;
            for (int d=0; d<768; d++) acc = fmaf(xr_m[d], (float)wr[d], acc);
            float hv = __fadd_rn(__fmul_rn(acc, g[gcol]), bb[gcol]);
            float vq = q8f(hv);
            float o = __fmul_rn(s_as, vq);
            float c6 = fminf(fmaxf(o+3.f, 0.f), 6.f);
            hq[t] = q8f(__fdiv_rn(__fmul_rn(o, c6), 6.f));
        }
        __syncthreads();
        #pragma unroll
        for (int cc=0; cc<3; cc++){
            int c = t + cc*256;
            float s = 0.f;
            for (int d=0; d<256; d++)
                s = fmaf(hq[d], q8f(proj_w[(size_t)c*3072 + h*256 + d]), s);
            atomicAdd(&out[((size_t)b*SEQ + n)*768 + c], __fmul_rn(pg[c], s));
        }
    }
}

extern "C" void kernel_launch(void* const* d_in, const int* in_sizes, int n_in,
                              void* d_out, int out_size, void* d_ws, size_t ws_size,
                              hipStream_t stream)
{
    const float* x       = (const float*)d_in[0];
    const float* qkv_w   = (const float*)d_in[1];
    const float* qkv_g   = (const float*)d_in[2];
    const float* qkv_b   = (const float*)d_in[3];
    const float* proj_w  = (const float*)d_in[4];
    const float* proj_g  = (const float*)d_in[5];
    const float* proj_b  = (const float*)d_in[6];
    const float* biases  = (const float*)d_in[7];
    const int NU = in_sizes[7] / NH;   // 1024

    char* w = (char*)d_ws;
    f16* xq  = (f16*)w; w += (size_t)8192*768*2;
    f16* wq  = (f16*)w; w += (size_t)4608*768*2;
    f16* Qm  = (f16*)w; w += (size_t)96*1024*64*2;
    f16* Km  = (f16*)w; w += (size_t)96*1024*64*2;
    int* cnt = (int*)w;  w += 16;
    int* cnt2= (int*)w;  w += 16;
    int2* entries = (int2*)w; w += (size_t)ECAP*8;
    int2* amb     = (int2*)w; w += (size_t)ECAP*8;

    quant_f16<<<6144, 256, 0, stream>>>(x,     xq, 8192*768);
    quant_f16<<<3456, 256, 0, stream>>>(qkv_w, wq, 4608*768);
    fill_out <<<6144, 256, 0, stream>>>((float*)d_out, proj_b, cnt, cnt2);

    gemm_qk<<<dim3(12,64), 256, 0, stream>>>(xq, wq, qkv_g, qkv_b, Qm, Km);

    pass_a<<<dim3(16,96), 256, 0, stream>>>(Qm, Km, biases, NU, cnt, entries, cnt2, amb);

    resolve_kernel<<<256, 256, 0, stream>>>(Qm, Km, biases, NU, cnt2, amb, cnt, entries);

    correct_kernel<<<256, 256, 0, stream>>>(xq, wq, qkv_g, qkv_b, biases, NU,
                                            proj_w, proj_g, cnt, entries, (float*)d_out);
}

// Round 8
// 87.971 us; speedup vs baseline: 1.1033x; 1.1033x over previous
//
#include <hip/hip_runtime.h>

typedef _Float16 f16;
typedef _Float16 f16x8 __attribute__((ext_vector_type(8)));
typedef _Float16 f16x4 __attribute__((ext_vector_type(4)));
typedef float    f32x4 __attribute__((ext_vector_type(4)));

#define MFMA16(a,b,c) __builtin_amdgcn_mfma_f32_16x16x32_f16((a),(b),(c),0,0,0)
#define AS1(p) ((const __attribute__((address_space(1))) void*)(p))
#define AS3(p) ((__attribute__((address_space(3))) void*)(p))

constexpr int   NH   = 12;
constexpr int   SEQ  = 1024;
constexpr float INV128 = 1.0f/128.0f;
constexpr int   ECAP = 98304;
constexpr float THR_NOT = -4.5948f;   // ln(1/0.99 - 1) rounded toward safe side

__device__ __forceinline__ float q8f(float x){ return rintf(x*128.0f)*INV128; }
__device__ __forceinline__ float q4f(float x){ return rintf(x*8.0f)*0.125f; }

// ---------------- K0: quantize fp32 -> fp16 (exact) ----------------
__global__ void quant_f16(const float* __restrict__ in, f16* __restrict__ out, int n){
    int i = (blockIdx.x*256 + threadIdx.x)*4;
    if (i >= n) return;
    float4 v = *(const float4*)(in + i);
    f16x4 o;
    o[0]=(f16)q8f(v.x); o[1]=(f16)q8f(v.y); o[2]=(f16)q8f(v.z); o[3]=(f16)q8f(v.w);
    *(f16x4*)(out + i) = o;
}

// ---------------- K_fill: out = proj_b broadcast; reset counters -------
__global__ void fill_out(float* __restrict__ out, const float* __restrict__ pb,
                         int* __restrict__ cnt, int* __restrict__ cnt2){
    int i = (blockIdx.x*256 + threadIdx.x)*4;
    int c = i % 768;
    float4 v = { pb[c], pb[c+1], pb[c+2], pb[c+3] };
    *(float4*)(out + i) = v;
    if (i == 0){ *cnt = 0; *cnt2 = 0; }
}

// ---------------- K_bmax: per-head max |bias| ----------------
__global__ void bias_max(const float* __restrict__ biases, int NU, float* __restrict__ Bh){
    int h = blockIdx.x, t = threadIdx.x;
    float m = 0.f;
    for (int i = t; i < NU; i += 256) m = fmaxf(m, fabsf(biases[h*NU + i]));
    #pragma unroll
    for (int d=32; d>=1; d>>=1) m = fmaxf(m, __shfl_xor(m, d));
    __shared__ float s[4];
    if ((t&63)==0) s[t>>6] = m;
    __syncthreads();
    if (t==0) Bh[h] = fmaxf(fmaxf(s[0],s[1]), fmaxf(s[2],s[3]));
}

// ---------------- K1: QK-only GEMM (8192x1536x768), m97-style ---------------
__global__ __launch_bounds__(256) void gemm_qk(
    const f16* __restrict__ Aq, const f16* __restrict__ Wq,
    const float* __restrict__ g, const float* __restrict__ bb,
    f16* __restrict__ Qm, f16* __restrict__ Km)
{
    __shared__ f16 As[128][32];
    __shared__ f16 Bs[128][32];
    const int t = threadIdx.x;
    const int head = blockIdx.x;
    const int row0 = blockIdx.y*128;
    const int wid = t>>6, lane = t&63;
    const int wr = (wid>>1)*64, wc = (wid&1)*64;
    const int lr = lane&15, lg = lane>>4;

    const f16* Asrc = Aq + (size_t)row0*768;
    const f16* Bsrc = Wq + (size_t)(head*384)*768;

    const int r0 = wid*32 + (lane>>2);
    const int scol = (lane&3)*8;
    const f16* a0p = Asrc + (size_t)r0*768 + scol;
    const f16* a1p = a0p + (size_t)16*768;
    const f16* b0p = Bsrc + (size_t)r0*768 + scol;
    const f16* b1p = b0p + (size_t)16*768;
    f16* lA0 = &As[wid*32][0];
    f16* lA1 = &As[wid*32+16][0];
    f16* lB0 = &Bs[wid*32][0];
    f16* lB1 = &Bs[wid*32+16][0];

    f32x4 acc[4][4] = {};
    for (int k0 = 0; k0 < 768; k0 += 32){
        __builtin_amdgcn_global_load_lds(AS1(a0p + k0), AS3(lA0), 16, 0, 0);
        __builtin_amdgcn_global_load_lds(AS1(a1p + k0), AS3(lA1), 16, 0, 0);
        __builtin_amdgcn_global_load_lds(AS1(b0p + k0), AS3(lB0), 16, 0, 0);
        __builtin_amdgcn_global_load_lds(AS1(b1p + k0), AS3(lB1), 16, 0, 0);
        __syncthreads();
        f16x8 af[4], bf[4];
        #pragma unroll
        for (int i=0;i<4;i++){
            af[i] = *(const f16x8*)&As[wr + i*16 + lr][lg*8];
            bf[i] = *(const f16x8*)&Bs[wc + i*16 + lr][lg*8];
        }
        #pragma unroll
        for (int i=0;i<4;i++)
            #pragma unroll
            for (int j=0;j<4;j++)
                acc[i][j] = MFMA16(af[i], bf[j], acc[i][j]);
        __syncthreads();
    }
    #pragma unroll
    for (int j=0;j<4;j++){
        int rr = wc + j*16 + lr;
        int gcol = head*384 + rr;
        float gg = g[gcol], bv = bb[gcol];
        #pragma unroll
        for (int i=0;i<4;i++){
            #pragma unroll
            for (int r=0;r<4;r++){
                int grow = row0 + wr + i*16 + lg*4 + r;
                float h = __fadd_rn(__fmul_rn(acc[i][j][r], gg), bv);
                float v4 = q4f(q8f(h));
                int bq = grow >> 10, n = grow & 1023;
                size_t base = ((size_t)(bq*NH + head)*SEQ + n)*64;
                if (rr < 64) Qm[base + rr]      = (f16)v4;
                else         Km[base + rr - 64] = (f16)(v4 * 0.125f);
            }
        }
    }
}

// ---------------- K2: pass A — bias-free max/second-max screen ----------
__global__ __launch_bounds__(256) void pass_a(
    const f16* __restrict__ Qm, const f16* __restrict__ Km,
    const float* __restrict__ Bh,
    int* __restrict__ cnt2, int2* __restrict__ amb)
{
    __shared__ f16 Ks[64][72];

    const int t = threadIdx.x;
    // XCD-chunked remap: all 16 q-tiles of one (b,h) land on one XCD
    const int bid = blockIdx.x;                 // 0..1535
    const int wg  = (bid & 7)*192 + (bid >> 3);
    const int bh  = wg >> 4;
    const int qt  = wg & 15;
    const int n0 = qt*64;
    const int lane = t&63, w = t>>6;
    const int lr = lane&15, lg = lane>>4;

    const float thr = THR_NOT + 2.0f*Bh[bh % NH] + 1e-4f;

    // direct global load of this lane's Q fragments (row w*16+lr of the 64-row tile)
    const f16* qp = &Qm[((size_t)bh*SEQ + n0 + w*16 + lr)*64];
    const f16x8 aq0 = *(const f16x8*)(qp + lg*8);
    const f16x8 aq1 = *(const f16x8*)(qp + 32 + lg*8);

    float mx[4], m2[4];
    #pragma unroll
    for (int r=0;r<4;r++){ mx[r] = -3e38f; m2[r] = -3e38f; }

    for (int kb = 0; kb < SEQ; kb += 64){
        __syncthreads();
        for (int sidx = t; sidx < 512; sidx += 256){
            int r = sidx>>3, q = (sidx&7)*8;
            *(f16x8*)&Ks[r][q] = *(const f16x8*)&Km[((size_t)bh*SEQ + kb + r)*64 + q];
        }
        __syncthreads();
        #pragma unroll
        for (int ct=0; ct<4; ct++){
            f16x8 b0 = *(const f16x8*)&Ks[ct*16+lr][lg*8];
            f16x8 b1 = *(const f16x8*)&Ks[ct*16+lr][32+lg*8];
            f32x4 c = {};
            c = MFMA16(aq0, b0, c);
            c = MFMA16(aq1, b1, c);
            #pragma unroll
            for (int r=0;r<4;r++){
                float sc = c[r];
                float om = mx[r];
                m2[r] = fmaxf(m2[r], fminf(sc, om));
                mx[r] = fmaxf(om, sc);
            }
        }
    }

    #pragma unroll
    for (int r=0;r<4;r++){
        float mxv = mx[r], m2v = m2[r];
        #pragma unroll
        for (int d=1; d<16; d<<=1){
            float mo  = __shfl_xor(mxv, d);
            float m2o = __shfl_xor(m2v, d);
            float sec = fmaxf(fminf(mxv, mo), (mxv >= mo) ? m2v : m2o);
            mxv = fmaxf(mxv, mo);
            m2v = sec;
        }
        if (lr == 0){
            if (m2v - mxv < thr){
                int n = n0 + w*16 + lg*4 + r;
                int pos = atomicAdd(cnt2, 1);
                if (pos < ECAP) amb[pos] = make_int2((bh<<10) | n, 0);
            }
        }
    }
}

// ---------------- K2b: exact biased resolve (flag + argmax) ----------
__global__ __launch_bounds__(256) void resolve_kernel(
    const f16* __restrict__ Qm, const f16* __restrict__ Km,
    const float* __restrict__ biases, int NU,
    const int* __restrict__ cnt2, const int2* __restrict__ amb,
    int* __restrict__ cnt, int2* __restrict__ entries)
{
    __shared__ float qrow[64];
    __shared__ float rmax[4], rsum[4];
    __shared__ int   rarg[4];
    int total = *cnt2; if (total > ECAP) total = ECAP;
    const int t = threadIdx.x;
    for (int e = blockIdx.x; e < total; e += gridDim.x){
        int2 a = amb[e];
        int bh = a.x>>10, n = a.x&1023, h = bh % NH;
        __syncthreads();
        if (t < 64) qrow[t] = (float)Qm[((size_t)bh*SEQ + n)*64 + t];
        __syncthreads();
        int rn = n>>5, cnn = n&31;
        float lmax = -3e38f; int larg = 0; float lsc[4];
        #pragma unroll
        for (int j=0;j<4;j++){
            int m = t + j*256;
            const f16* kp = &Km[((size_t)bh*SEQ + m)*64];
            float d = 0.f;
            for (int u=0; u<64; u+=8){
                f16x8 kv = *(const f16x8*)(kp+u);
                #pragma unroll
                for (int z=0; z<8; z++) d += qrow[u+z]*(float)kv[z];
            }
            int idx = __builtin_abs(rn-(m>>5))*32 + __builtin_abs(cnn-(m&31));
            lsc[j] = d + biases[h*NU + idx];
            if (lsc[j] > lmax){ lmax = lsc[j]; larg = m; }
        }
        #pragma unroll
        for (int dd=32; dd>=1; dd>>=1){
            float mo = __shfl_xor(lmax, dd);
            int   ao = __shfl_xor(larg, dd);
            if (mo > lmax){ lmax = mo; larg = ao; }
        }
        if ((t&63)==0){ rmax[t>>6] = lmax; rarg[t>>6] = larg; }
        __syncthreads();
        float MX = rmax[0]; int ARG = rarg[0];
        #pragma unroll
        for (int k=1;k<4;k++){ if (rmax[k] > MX){ MX = rmax[k]; ARG = rarg[k]; } }
        float ls = 0.f;
        #pragma unroll
        for (int j=0;j<4;j++) ls += expf(lsc[j]-MX);
        #pragma unroll
        for (int dd=32; dd>=1; dd>>=1) ls += __shfl_xor(ls, dd);
        if ((t&63)==0) rsum[t>>6] = ls;
        __syncthreads();
        if (t==0){
            float SUM = rsum[0]+rsum[1]+rsum[2]+rsum[3];
            if (1.0f/SUM > 0.99f){
                int pos = atomicAdd(cnt, 1);
                if (pos < ECAP) entries[pos] = make_int2(a.x, ARG);
            }
        }
    }
}

// ---------------- K3: rare-path exact correction (recomputes q,k,v) --------
__global__ __launch_bounds__(256) void correct_kernel(
    const f16* __restrict__ xq, const f16* __restrict__ wq,
    const float* __restrict__ g, const float* __restrict__ bb,
    const float* __restrict__ biases, int NU,
    const float* __restrict__ proj_w, const float* __restrict__ pg,
    const int* __restrict__ cnt, const int2* __restrict__ entries,
    float* __restrict__ out)
{
    __shared__ float xr_n[768], xr_m[768];
    __shared__ float qs[64], ks[64];
    __shared__ float hq[256];
    __shared__ float s_as;
    int total = *cnt; if (total > ECAP) total = ECAP;
    const int t = threadIdx.x;
    for (int e = blockIdx.x; e < total; e += gridDim.x){
        int2 a = entries[e];
        int bh = a.x>>10, n = a.x&1023, ms = a.y;
        int h = bh % NH, b = bh / NH;
        __syncthreads();
        for (int i=t; i<768; i+=256){
            xr_n[i] = (float)xq[((size_t)b*SEQ + n)*768 + i];
            xr_m[i] = (float)xq[((size_t)b*SEQ + ms)*768 + i];
        }
        __syncthreads();
        if (t < 128){
            int col = t & 63;
            int gcol = h*384 + (t<64 ? col : 64+col);
            const f16* wr = &wq[(size_t)gcol*768];
            const float* xr = (t<64) ? xr_n : xr_m;
            float acc = 0.f;
            for (int d=0; d<768; d++) acc = fmaf(xr[d], (float)wr[d], acc);
            float hv = __fadd_rn(__fmul_rn(acc, g[gcol]), bb[gcol]);
            float v = q8f(hv);
            if (t<64) qs[col] = v; else ks[col] = v;
        }
        __syncthreads();
        if (t < 64){
            float p = qs[t]*ks[t];
            #pragma unroll
            for (int d=32; d>=1; d>>=1) p += __shfl_xor(p, d);
            if (t == 0){
                int idx = __builtin_abs((n>>5)-(ms>>5))*32 + __builtin_abs((n&31)-(ms&31));
                float ss = __fadd_rn(__fmul_rn(p, 0.125f), biases[h*NU + idx]);
                float mx2 = fmaxf(ss, 0.f);
                float es = expf(ss-mx2), e0 = expf(-mx2);
                float Z = fmaf(1023.f, e0, es);
                s_as = q8f(es/Z);     // off-argmax weights quantize to exactly 0
            }
        }
        __syncthreads();
        {
            int gcol = h*384 + 128 + t;
            const f16* wr = &wq[(size_t)gcol*768];
            float acc = 0.f;
            for (int d=0; d<768; d++) acc = fmaf(xr_m[d], (float)wr[d], acc);
            float hv = __fadd_rn(__fmul_rn(acc, g[gcol]), bb[gcol]);
            float vq = q8f(hv);
            float o = __fmul_rn(s_as, vq);
            float c6 = fminf(fmaxf(o+3.f, 0.f), 6.f);
            hq[t] = q8f(__fdiv_rn(__fmul_rn(o, c6), 6.f));
        }
        __syncthreads();
        #pragma unroll
        for (int cc=0; cc<3; cc++){
            int c = t + cc*256;
            float s = 0.f;
            for (int d=0; d<256; d++)
                s = fmaf(hq[d], q8f(proj_w[(size_t)c*3072 + h*256 + d]), s);
            atomicAdd(&out[((size_t)b*SEQ + n)*768 + c], __fmul_rn(pg[c], s));
        }
    }
}

extern "C" void kernel_launch(void* const* d_in, const int* in_sizes, int n_in,
                              void* d_out, int out_size, void* d_ws, size_t ws_size,
                              hipStream_t stream)
{
    const float* x       = (const float*)d_in[0];
    const float* qkv_w   = (const float*)d_in[1];
    const float* qkv_g   = (const float*)d_in[2];
    const float* qkv_b   = (const float*)d_in[3];
    const float* proj_w  = (const float*)d_in[4];
    const float* proj_g  = (const float*)d_in[5];
    const float* proj_b  = (const float*)d_in[6];
    const float* biases  = (const float*)d_in[7];
    const int NU = in_sizes[7] / NH;   // 1024

    char* w = (char*)d_ws;
    f16* xq  = (f16*)w; w += (size_t)8192*768*2;
    f16* wq  = (f16*)w; w += (size_t)4608*768*2;
    f16* Qm  = (f16*)w; w += (size_t)96*1024*64*2;
    f16* Km  = (f16*)w; w += (size_t)96*1024*64*2;
    int* cnt = (int*)w;  w += 16;
    int* cnt2= (int*)w;  w += 16;
    float* Bh = (float*)w; w += 64;
    int2* entries = (int2*)w; w += (size_t)ECAP*8;
    int2* amb     = (int2*)w; w += (size_t)ECAP*8;

    quant_f16<<<6144, 256, 0, stream>>>(x,     xq, 8192*768);
    quant_f16<<<3456, 256, 0, stream>>>(qkv_w, wq, 4608*768);
    fill_out <<<6144, 256, 0, stream>>>((float*)d_out, proj_b, cnt, cnt2);
    bias_max <<<NH,   256, 0, stream>>>(biases, NU, Bh);

    gemm_qk<<<dim3(12,64), 256, 0, stream>>>(xq, wq, qkv_g, qkv_b, Qm, Km);

    pass_a<<<1536, 256, 0, stream>>>(Qm, Km, Bh, cnt2, amb);

    resolve_kernel<<<256, 256, 0, stream>>>(Qm, Km, biases, NU, cnt2, amb, cnt, entries);

    correct_kernel<<<256, 256, 0, stream>>>(xq, wq, qkv_g, qkv_b, biases, NU,
                                            proj_w, proj_g, cnt, entries, (float*)d_out);
}

// Round 9
// 83.015 us; speedup vs baseline: 1.1692x; 1.0597x over previous
//
#include <hip/hip_runtime.h>

typedef _Float16 f16;
typedef _Float16 f16x8 __attribute__((ext_vector_type(8)));
typedef _Float16 f16x4 __attribute__((ext_vector_type(4)));
typedef float    f32x4 __attribute__((ext_vector_type(4)));

#define MFMA16(a,b,c) __builtin_amdgcn_mfma_f32_16x16x32_f16((a),(b),(c),0,0,0)
#define AS1(p) ((const __attribute__((address_space(1))) void*)(p))
#define AS3(p) ((__attribute__((address_space(3))) void*)(p))

constexpr int   NH   = 12;
constexpr int   SEQ  = 1024;
constexpr float INV128 = 1.0f/128.0f;
constexpr int   ECAP = 98304;
constexpr float THR_NOT = -4.5948f;   // ln(1/0.99 - 1) rounded toward safe side

__device__ __forceinline__ float q8f(float x){ return rintf(x*128.0f)*INV128; }
__device__ __forceinline__ float q4f(float x){ return rintf(x*8.0f)*0.125f; }

// ---------------- K0: merged prelude ----------------
// blocks [0,6144): xq = q8(x)            (6291456 elems)
// blocks [6144,9600): wq = q8(qkv_w)     (3538944 elems)
// blocks [9600,15744): out = proj_b broadcast
// blocks [15744,15756): Bh[h] = max|bias_h| ; block 15744 resets counters
__global__ __launch_bounds__(256) void prelude(
    const float* __restrict__ x, const float* __restrict__ qkv_w,
    float* __restrict__ out, const float* __restrict__ pb,
    const float* __restrict__ biases, int NU,
    f16* __restrict__ xq, f16* __restrict__ wq,
    float* __restrict__ Bh, int* __restrict__ cnt, int* __restrict__ cnt2)
{
    const int b = blockIdx.x, t = threadIdx.x;
    if (b < 6144){
        int i = (b*256 + t)*4;
        float4 v = *(const float4*)(x + i);
        f16x4 o;
        o[0]=(f16)q8f(v.x); o[1]=(f16)q8f(v.y); o[2]=(f16)q8f(v.z); o[3]=(f16)q8f(v.w);
        *(f16x4*)(xq + i) = o;
    } else if (b < 9600){
        int i = ((b-6144)*256 + t)*4;
        float4 v = *(const float4*)(qkv_w + i);
        f16x4 o;
        o[0]=(f16)q8f(v.x); o[1]=(f16)q8f(v.y); o[2]=(f16)q8f(v.z); o[3]=(f16)q8f(v.w);
        *(f16x4*)(wq + i) = o;
    } else if (b < 15744){
        int i = ((b-9600)*256 + t)*4;
        int c = i % 768;
        float4 v = { pb[c], pb[c+1], pb[c+2], pb[c+3] };
        *(float4*)(out + i) = v;
    } else {
        int h = b - 15744;
        float m = 0.f;
        for (int i = t; i < NU; i += 256) m = fmaxf(m, fabsf(biases[h*NU + i]));
        #pragma unroll
        for (int d=32; d>=1; d>>=1) m = fmaxf(m, __shfl_xor(m, d));
        __shared__ float s[4];
        if ((t&63)==0) s[t>>6] = m;
        __syncthreads();
        if (t==0){
            Bh[h] = fmaxf(fmaxf(s[0],s[1]), fmaxf(s[2],s[3]));
            if (h==0){ *cnt = 0; *cnt2 = 0; }
        }
    }
}

// ---------------- K1: QK-only GEMM, BK=64 dbuf + T2 swizzle + counted vmcnt ----
__global__ __launch_bounds__(256) void gemm_qk(
    const f16* __restrict__ Aq, const f16* __restrict__ Wq,
    const float* __restrict__ g, const float* __restrict__ bb,
    f16* __restrict__ Qm, f16* __restrict__ Km)
{
    __shared__ f16 As[2][128][64];
    __shared__ f16 Bs[2][128][64];
    const int t = threadIdx.x;
    const int head = blockIdx.x;
    const int row0 = blockIdx.y*128;
    const int wid = t>>6, lane = t&63;
    const int wr = (wid>>1)*64, wc = (wid&1)*64;
    const int lr = lane&15, lg = lane>>4;

    const f16* Asrc = Aq + (size_t)row0*768;
    const f16* Bsrc = Wq + (size_t)(head*384)*768;

    // staging geometry: instruction i of wave wid covers tile rows (wid*4+i)*8 .. +7.
    // lane -> row_local = lane>>3, lds slot = lane&7; source slot = slot ^ (row&7)
    const int rloc  = lane>>3;
    const int gslot = (lane&7) ^ rloc;
    const int srcColOff = gslot*8;   // f16 elements

    f32x4 acc[4][4] = {};

    // prologue: stage K-tile 0 into buf 0
    #pragma unroll
    for (int i=0;i<4;i++){
        int rr = (wid*4+i)*8 + rloc;
        __builtin_amdgcn_global_load_lds(AS1(Asrc + (size_t)rr*768 + srcColOff),
                                         AS3(&As[0][(wid*4+i)*8][0]), 16, 0, 0);
        __builtin_amdgcn_global_load_lds(AS1(Bsrc + (size_t)rr*768 + srcColOff),
                                         AS3(&Bs[0][(wid*4+i)*8][0]), 16, 0, 0);
    }

    int cur = 0;
    for (int kt = 0; kt < 12; kt++){
        // barrier 1: everyone finished reading buf[cur^1] (previous iter) before overwrite
        __builtin_amdgcn_s_barrier();
        if (kt < 11){
            const int k0 = (kt+1)*64;
            #pragma unroll
            for (int i=0;i<4;i++){
                int rr = (wid*4+i)*8 + rloc;
                __builtin_amdgcn_global_load_lds(AS1(Asrc + (size_t)rr*768 + k0 + srcColOff),
                                                 AS3(&As[cur^1][(wid*4+i)*8][0]), 16, 0, 0);
                __builtin_amdgcn_global_load_lds(AS1(Bsrc + (size_t)rr*768 + k0 + srcColOff),
                                                 AS3(&Bs[cur^1][(wid*4+i)*8][0]), 16, 0, 0);
            }
            asm volatile("s_waitcnt vmcnt(8)" ::: "memory");   // buf[cur] loads (oldest 8) done
        } else {
            asm volatile("s_waitcnt vmcnt(0)" ::: "memory");
        }
        __builtin_amdgcn_s_barrier();   // barrier 2: buf[cur] visible to all waves

        #pragma unroll
        for (int kk=0; kk<2; kk++){
            f16x8 af[4], bf[4];
            #pragma unroll
            for (int i=0;i<4;i++){
                int rA = wr + i*16 + lr;
                int rB = wc + i*16 + lr;
                af[i] = *(const f16x8*)&As[cur][rA][(((lg + kk*4) ^ (rA&7)))*8];
                bf[i] = *(const f16x8*)&Bs[cur][rB][(((lg + kk*4) ^ (rB&7)))*8];
            }
            #pragma unroll
            for (int i=0;i<4;i++)
                #pragma unroll
                for (int j=0;j<4;j++)
                    acc[i][j] = MFMA16(af[i], bf[j], acc[i][j]);
        }
        cur ^= 1;
    }

    #pragma unroll
    for (int j=0;j<4;j++){
        int rr = wc + j*16 + lr;
        int gcol = head*384 + rr;
        float gg = g[gcol], bv = bb[gcol];
        #pragma unroll
        for (int i=0;i<4;i++){
            #pragma unroll
            for (int r=0;r<4;r++){
                int grow = row0 + wr + i*16 + lg*4 + r;
                float h = __fadd_rn(__fmul_rn(acc[i][j][r], gg), bv);
                float v4 = q4f(q8f(h));
                int bq = grow >> 10, n = grow & 1023;
                size_t base = ((size_t)(bq*NH + head)*SEQ + n)*64;
                if (rr < 64) Qm[base + rr]      = (f16)v4;
                else         Km[base + rr - 64] = (f16)(v4 * 0.125f);
            }
        }
    }
}

// ---------------- K2: pass A — bias-free max/second-max screen ----------
__global__ __launch_bounds__(256) void pass_a(
    const f16* __restrict__ Qm, const f16* __restrict__ Km,
    const float* __restrict__ Bh,
    int* __restrict__ cnt2, int2* __restrict__ amb)
{
    __shared__ f16 Ks[128][72];

    const int t = threadIdx.x;
    // XCD-chunked remap: all 16 q-tiles of one (b,h) land on one XCD
    const int bid = blockIdx.x;                 // 0..1535
    const int wg  = (bid & 7)*192 + (bid >> 3);
    const int bh  = wg >> 4;
    const int qt  = wg & 15;
    const int n0 = qt*64;
    const int lane = t&63, w = t>>6;
    const int lr = lane&15, lg = lane>>4;

    const float thr = THR_NOT + 2.0f*Bh[bh % NH] + 1e-4f;

    const f16* qp = &Qm[((size_t)bh*SEQ + n0 + w*16 + lr)*64];
    const f16x8 aq0 = *(const f16x8*)(qp + lg*8);
    const f16x8 aq1 = *(const f16x8*)(qp + 32 + lg*8);

    float mx[4], m2[4];
    #pragma unroll
    for (int r=0;r<4;r++){ mx[r] = -3e38f; m2[r] = -3e38f; }

    for (int kb = 0; kb < SEQ; kb += 128){
        __syncthreads();
        for (int sidx = t; sidx < 1024; sidx += 256){
            int r = sidx>>3, q = (sidx&7)*8;
            *(f16x8*)&Ks[r][q] = *(const f16x8*)&Km[((size_t)bh*SEQ + kb + r)*64 + q];
        }
        __syncthreads();
        #pragma unroll
        for (int ct=0; ct<8; ct++){
            f16x8 b0 = *(const f16x8*)&Ks[ct*16+lr][lg*8];
            f16x8 b1 = *(const f16x8*)&Ks[ct*16+lr][32+lg*8];
            f32x4 c = {};
            c = MFMA16(aq0, b0, c);
            c = MFMA16(aq1, b1, c);
            #pragma unroll
            for (int r=0;r<4;r++){
                float sc = c[r];
                float om = mx[r];
                m2[r] = fmaxf(m2[r], fminf(sc, om));
                mx[r] = fmaxf(om, sc);
            }
        }
    }

    #pragma unroll
    for (int r=0;r<4;r++){
        float mxv = mx[r], m2v = m2[r];
        #pragma unroll
        for (int d=1; d<16; d<<=1){
            float mo  = __shfl_xor(mxv, d);
            float m2o = __shfl_xor(m2v, d);
            float sec = fmaxf(fminf(mxv, mo), (mxv >= mo) ? m2v : m2o);
            mxv = fmaxf(mxv, mo);
            m2v = sec;
        }
        if (lr == 0){
            if (m2v - mxv < thr){
                int n = n0 + w*16 + lg*4 + r;
                int pos = atomicAdd(cnt2, 1);
                if (pos < ECAP) amb[pos] = make_int2((bh<<10) | n, 0);
            }
        }
    }
}

// ---------------- K2b: exact biased resolve (flag + argmax) ----------
__global__ __launch_bounds__(256) void resolve_kernel(
    const f16* __restrict__ Qm, const f16* __restrict__ Km,
    const float* __restrict__ biases, int NU,
    const int* __restrict__ cnt2, const int2* __restrict__ amb,
    int* __restrict__ cnt, int2* __restrict__ entries)
{
    __shared__ float qrow[64];
    __shared__ float rmax[4], rsum[4];
    __shared__ int   rarg[4];
    int total = *cnt2; if (total > ECAP) total = ECAP;
    const int t = threadIdx.x;
    for (int e = blockIdx.x; e < total; e += gridDim.x){
        int2 a = amb[e];
        int bh = a.x>>10, n = a.x&1023, h = bh % NH;
        __syncthreads();
        if (t < 64) qrow[t] = (float)Qm[((size_t)bh*SEQ + n)*64 + t];
        __syncthreads();
        int rn = n>>5, cnn = n&31;
        float lmax = -3e38f; int larg = 0; float lsc[4];
        #pragma unroll
        for (int j=0;j<4;j++){
            int m = t + j*256;
            const f16* kp = &Km[((size_t)bh*SEQ + m)*64];
            float d = 0.f;
            for (int u=0; u<64; u+=8){
                f16x8 kv = *(const f16x8*)(kp+u);
                #pragma unroll
                for (int z=0; z<8; z++) d += qrow[u+z]*(float)kv[z];
            }
            int idx = __builtin_abs(rn-(m>>5))*32 + __builtin_abs(cnn-(m&31));
            lsc[j] = d + biases[h*NU + idx];
            if (lsc[j] > lmax){ lmax = lsc[j]; larg = m; }
        }
        #pragma unroll
        for (int dd=32; dd>=1; dd>>=1){
            float mo = __shfl_xor(lmax, dd);
            int   ao = __shfl_xor(larg, dd);
            if (mo > lmax){ lmax = mo; larg = ao; }
        }
        if ((t&63)==0){ rmax[t>>6] = lmax; rarg[t>>6] = larg; }
        __syncthreads();
        float MX = rmax[0]; int ARG = rarg[0];
        #pragma unroll
        for (int k=1;k<4;k++){ if (rmax[k] > MX){ MX = rmax[k]; ARG = rarg[k]; } }
        float ls = 0.f;
        #pragma unroll
        for (int j=0;j<4;j++) ls += expf(lsc[j]-MX);
        #pragma unroll
        for (int dd=32; dd>=1; dd>>=1) ls += __shfl_xor(ls, dd);
        if ((t&63)==0) rsum[t>>6] = ls;
        __syncthreads();
        if (t==0){
            float SUM = rsum[0]+rsum[1]+rsum[2]+rsum[3];
            if (1.0f/SUM > 0.99f){
                int pos = atomicAdd(cnt, 1);
                if (pos < ECAP) entries[pos] = make_int2(a.x, ARG);
            }
        }
    }
}

// ---------------- K3: rare-path exact correction (recomputes q,k,v) --------
__global__ __launch_bounds__(256) void correct_kernel(
    const f16* __restrict__ xq, const f16* __restrict__ wq,
    const float* __restrict__ g, const float* __restrict__ bb,
    const float* __restrict__ biases, int NU,
    const float* __restrict__ proj_w, const float* __restrict__ pg,
    const int* __restrict__ cnt, const int2* __restrict__ entries,
    float* __restrict__ out)
{
    __shared__ float xr_n[768], xr_m[768];
    __shared__ float qs[64], ks[64];
    __shared__ float hq[256];
    __shared__ float s_as;
    int total = *cnt; if (total > ECAP) total = ECAP;
    const int t = threadIdx.x;
    for (int e = blockIdx.x; e < total; e += gridDim.x){
        int2 a = entries[e];
        int bh = a.x>>10, n = a.x&1023, ms = a.y;
        int h = bh % NH, b = bh / NH;
        __syncthreads();
        for (int i=t; i<768; i+=256){
            xr_n[i] = (float)xq[((size_t)b*SEQ + n)*768 + i];
            xr_m[i] = (float)xq[((size_t)b*SEQ + ms)*768 + i];
        }
        __syncthreads();
        if (t < 128){
            int col = t & 63;
            int gcol = h*384 + (t<64 ? col : 64+col);
            const f16* wr = &wq[(size_t)gcol*768];
            const float* xr = (t<64) ? xr_n : xr_m;
            float acc = 0.f;
            for (int d=0; d<768; d++) acc = fmaf(xr[d], (float)wr[d], acc);
            float hv = __fadd_rn(__fmul_rn(acc, g[gcol]), bb[gcol]);
            float v = q8f(hv);
            if (t<64) qs[col] = v; else ks[col] = v;
        }
        __syncthreads();
        if (t < 64){
            float p = qs[t]*ks[t];
            #pragma unroll
            for (int d=32; d>=1; d>>=1) p += __shfl_xor(p, d);
            if (t == 0){
                int idx = __builtin_abs((n>>5)-(ms>>5))*32 + __builtin_abs((n&31)-(ms&31));
                float ss = __fadd_rn(__fmul_rn(p, 0.125f), biases[h*NU + idx]);
                float mx2 = fmaxf(ss, 0.f);
                float es = expf(ss-mx2), e0 = expf(-mx2);
                float Z = fmaf(1023.f, e0, es);
                s_as = q8f(es/Z);     // off-argmax weights quantize to exactly 0
            }
        }
        __syncthreads();
        {
            int gcol = h*384 + 128 + t;
            const f16* wr = &wq[(size_t)gcol*768];
            float acc = 0.f;
            for (int d=0; d<768; d++) acc = fmaf(xr_m[d], (float)wr[d], acc);
            float hv = __fadd_rn(__fmul_rn(acc, g[gcol]), bb[gcol]);
            float vq = q8f(hv);
            float o = __fmul_rn(s_as, vq);
            float c6 = fminf(fmaxf(o+3.f, 0.f), 6.f);
            hq[t] = q8f(__fdiv_rn(__fmul_rn(o, c6), 6.f));
        }
        __syncthreads();
        #pragma unroll
        for (int cc=0; cc<3; cc++){
            int c = t + cc*256;
            float s = 0.f;
            for (int d=0; d<256; d++)
                s = fmaf(hq[d], q8f(proj_w[(size_t)c*3072 + h*256 + d]), s);
            atomicAdd(&out[((size_t)b*SEQ + n)*768 + c], __fmul_rn(pg[c], s));
        }
    }
}

extern "C" void kernel_launch(void* const* d_in, const int* in_sizes, int n_in,
                              void* d_out, int out_size, void* d_ws, size_t ws_size,
                              hipStream_t stream)
{
    const float* x       = (const float*)d_in[0];
    const float* qkv_w   = (const float*)d_in[1];
    const float* qkv_g   = (const float*)d_in[2];
    const float* qkv_b   = (const float*)d_in[3];
    const float* proj_w  = (const float*)d_in[4];
    const float* proj_g  = (const float*)d_in[5];
    const float* proj_b  = (const float*)d_in[6];
    const float* biases  = (const float*)d_in[7];
    const int NU = in_sizes[7] / NH;   // 1024

    char* w = (char*)d_ws;
    f16* xq  = (f16*)w; w += (size_t)8192*768*2;
    f16* wq  = (f16*)w; w += (size_t)4608*768*2;
    f16* Qm  = (f16*)w; w += (size_t)96*1024*64*2;
    f16* Km  = (f16*)w; w += (size_t)96*1024*64*2;
    int* cnt = (int*)w;  w += 16;
    int* cnt2= (int*)w;  w += 16;
    float* Bh = (float*)w; w += 64;
    int2* entries = (int2*)w; w += (size_t)ECAP*8;
    int2* amb     = (int2*)w; w += (size_t)ECAP*8;

    prelude<<<15756, 256, 0, stream>>>(x, qkv_w, (float*)d_out, proj_b, biases, NU,
                                       xq, wq, Bh, cnt, cnt2);

    gemm_qk<<<dim3(12,64), 256, 0, stream>>>(xq, wq, qkv_g, qkv_b, Qm, Km);

    pass_a<<<1536, 256, 0, stream>>>(Qm, Km, Bh, cnt2, amb);

    resolve_kernel<<<256, 256, 0, stream>>>(Qm, Km, biases, NU, cnt2, amb, cnt, entries);

    correct_kernel<<<256, 256, 0, stream>>>(xq, wq, qkv_g, qkv_b, biases, NU,
                                            proj_w, proj_g, cnt, entries, (float*)d_out);
}